// Round 11
// baseline (369.697 us; speedup 1.0000x reference)
//
#include <hip/hip_runtime.h>
#include <hip/hip_bf16.h>

#define B_ 4
#define H_ 16
#define L_ 2048
#define D_ 1024
#define DK_ 64

typedef __attribute__((ext_vector_type(8))) __bf16 bf16x8;
typedef __attribute__((ext_vector_type(4))) __bf16 bf16x4;
typedef __attribute__((ext_vector_type(4))) float f32x4;

#define MFMA16(a, b, c) __builtin_amdgcn_mfma_f32_16x16x32_bf16(a, b, c, 0, 0, 0)

typedef const __attribute__((address_space(1))) void gv_t;
typedef __attribute__((address_space(3))) void lv_t;

// ---------------------------------------------------------------------------
// Staging (rule #21): LDS dest linear + wave-uniform base + lane*16B; global
// SOURCE inverse-XOR-swizzled (slot s fetches slot s^(row&7)) so a swizzled
// read (byte ^ ((row&7)<<4)) recovers data ~conflict-free.
// 256-thread version: 32 rows/iter.  512-thread version: 64 rows/iter.
// ---------------------------------------------------------------------------
template<int NI>
__device__ __forceinline__ void stage_swz(const __bf16* __restrict__ g,
                                          size_t gstride, __bf16* lds, int t)
{
    const int wave = t >> 6;
#pragma unroll
    for (int i = 0; i < NI; ++i) {
        const int row = i * 32 + (t >> 3);
        const int s   = (t & 7) ^ (row & 7);
        __builtin_amdgcn_global_load_lds(
            (gv_t*)(g + (size_t)row * gstride + s * 8),
            (lv_t*)(lds + (size_t)(i * 32 + wave * 8) * 64),
            16, 0, 0);
    }
}

template<int NI>
__device__ __forceinline__ void stage512(const __bf16* __restrict__ g,
                                         size_t gstride, __bf16* lds, int t)
{
    const int wave = t >> 6;
#pragma unroll
    for (int i = 0; i < NI; ++i) {
        const int row = i * 64 + (t >> 3);
        const int s   = (t & 7) ^ (row & 7);
        __builtin_amdgcn_global_load_lds(
            (gv_t*)(g + (size_t)row * gstride + s * 8),
            (lv_t*)(lds + (size_t)(i * 64 + wave * 8) * 64),
            16, 0, 0);
    }
}

__device__ __forceinline__ bf16x8 lds_frag(const __bf16* base, int row, int kbyte)
{
    const char* p = (const char*)base + row * 128 + (kbyte ^ ((row & 7) << 4));
    return *(const bf16x8*)p;
}

// ---------------------------------------------------------------------------
// cast fp32 -> bf16, 7 segments
// ---------------------------------------------------------------------------
struct CastArgs {
    const float* s[7];
    __bf16*      d[7];
    int          n[7];
};

__global__ __launch_bounds__(256)
void cast_all(CastArgs a)
{
    const int seg = blockIdx.y;
    const int n   = a.n[seg];
    const float* __restrict__ s = a.s[seg];
    __bf16* __restrict__ d = a.d[seg];
    for (int i = (blockIdx.x * 256 + threadIdx.x) * 8; i < n; i += gridDim.x * 256 * 8) {
        float4 f0 = *reinterpret_cast<const float4*>(&s[i]);
        float4 f1 = *reinterpret_cast<const float4*>(&s[i + 4]);
        bf16x8 v;
        v[0] = (__bf16)f0.x; v[1] = (__bf16)f0.y; v[2] = (__bf16)f0.z; v[3] = (__bf16)f0.w;
        v[4] = (__bf16)f1.x; v[5] = (__bf16)f1.y; v[6] = (__bf16)f1.z; v[7] = (__bf16)f1.w;
        *reinterpret_cast<bf16x8*>(&d[i]) = v;
    }
}

// ---------------------------------------------------------------------------
// Big-tile bf16 GEMM: BM=256, BN=128, BK=64, 512 threads = 8 waves (4x2),
// wave tile 64x64 (4x4 frags), 2-phase double-buffered staging (validated
// structure: STAGE(t+1) -> compute(t) -> one barrier). LDS 96KB, 1 block/CU,
// launch_bounds(512,2). M=8192, K=1024 fixed.
// Grid: 8 XCDs x 4 m-panels x (N/128) n-cols; per-XCD inner order is
// m-fastest so each W col-panel (256KB) is L2-reused 4x; A panels (2MB)
// stay L2-resident per XCD.
// MODE 2: C = A*W^T + bias, fp32 flat [M,N]
// MODE 3: fused QKV: N=3072, which=n0>>10 picks A segment (q/k/v) and
//         output (Q/K head-split bf16 [B,H,L,DK]; V transposed [B,H,DK,L]).
// ---------------------------------------------------------------------------
struct QKVDst {
    const float* bq; const float* bk; const float* bvv;
    __bf16* qh; __bf16* kh; __bf16* vt;
};

#define ASEG ((size_t)B_ * L_ * D_)

template<int MODE>
__global__ __launch_bounds__(512, 2)
void gemm_big(const __bf16* __restrict__ A, const __bf16* __restrict__ W,
              const float* __restrict__ bias, void* __restrict__ Cout,
              int N, QKVDst qd)
{
    constexpr int BM = 256, BN = 128, BK = 64, K = 1024;
    __shared__ __bf16 As[2][BM * BK];
    __shared__ __bf16 Bs[2][BN * BK];

    const int t = threadIdx.x;
    const int wave = t >> 6, lane = t & 63;
    const int g4 = lane >> 4, l16 = lane & 15;
    const int wr = wave >> 1, wc = wave & 1;      // 4x2 wave grid
    const int fid = blockIdx.x;
    const int xcd = fid & 7;
    const int idx = fid >> 3;
    const int m0 = (xcd * 4 + (idx & 3)) * BM;    // 32 m-panels, 4 per XCD
    const int n0 = (idx >> 2) * BN;
    const int which = (MODE == 3) ? (n0 >> 10) : 0;   // uniform per block
    const __bf16* Ap = (MODE == 3) ? A + (size_t)which * ASEG : A;

    f32x4 acc[4][4];
#pragma unroll
    for (int m = 0; m < 4; ++m)
#pragma unroll
        for (int n = 0; n < 4; ++n) acc[m][n] = {0.f, 0.f, 0.f, 0.f};

    stage512<4>(Ap + (size_t)m0 * K, (size_t)K, As[0], t);
    stage512<2>(W  + (size_t)n0 * K, (size_t)K, Bs[0], t);
    __syncthreads();

    int cur = 0;
    for (int ti = 0; ti < K / BK; ++ti) {
        if (ti + 1 < K / BK) {
            stage512<4>(Ap + (size_t)m0 * K + (ti + 1) * BK, (size_t)K, As[cur ^ 1], t);
            stage512<2>(W  + (size_t)n0 * K + (ti + 1) * BK, (size_t)K, Bs[cur ^ 1], t);
        }
#pragma unroll
        for (int kk = 0; kk < 2; ++kk) {
            bf16x8 af[4], bfr[4];
#pragma unroll
            for (int m = 0; m < 4; ++m)
                af[m] = lds_frag(As[cur], wr * 64 + m * 16 + l16, kk * 64 + g4 * 16);
#pragma unroll
            for (int n = 0; n < 4; ++n)
                bfr[n] = lds_frag(Bs[cur], wc * 64 + n * 16 + l16, kk * 64 + g4 * 16);
#pragma unroll
            for (int m = 0; m < 4; ++m)
#pragma unroll
                for (int n = 0; n < 4; ++n)
                    acc[m][n] = MFMA16(af[m], bfr[n], acc[m][n]);
        }
        __syncthreads();   // drains vmcnt -> next buffer staged; 1/K-step
        cur ^= 1;
    }

#pragma unroll
    for (int n = 0; n < 4; ++n) {
        const int gc = n0 + wc * 64 + n * 16 + l16;
        float bval;
        int dd = gc, hh = 0, dk = 0;
        if (MODE == 3) {
            dd = gc & 1023; hh = dd >> 6; dk = dd & 63;
            const float* bp = (which == 0) ? qd.bq : (which == 1) ? qd.bk : qd.bvv;
            bval = bp[dd];
        } else {
            bval = bias[gc];
        }
#pragma unroll
        for (int m = 0; m < 4; ++m) {
            const int gr0 = m0 + wr * 64 + m * 16 + g4 * 4;
            if (MODE == 3) {
                const int bb = gr0 >> 11, l0 = gr0 & (L_ - 1);
                if (which < 2) {
                    __bf16* dst = (which == 0) ? qd.qh : qd.kh;
#pragma unroll
                    for (int r = 0; r < 4; ++r)
                        dst[(((size_t)(bb * H_ + hh)) * L_ + l0 + r) * DK_ + dk] =
                            (__bf16)(acc[m][n][r] + bval);
                } else {
                    bf16x4 v;
#pragma unroll
                    for (int r = 0; r < 4; ++r) v[r] = (__bf16)(acc[m][n][r] + bval);
                    *reinterpret_cast<bf16x4*>(
                        &qd.vt[(((size_t)(bb * H_ + hh)) * DK_ + dk) * L_ + l0]) = v;
                }
            } else {
#pragma unroll
                for (int r = 0; r < 4; ++r)
                    ((float*)Cout)[(size_t)(gr0 + r) * N + gc] = acc[m][n][r] + bval;
            }
        }
    }
}

// ---------------------------------------------------------------------------
// Causal flash attention (UNCHANGED, validated at 82 us):
// swapped QK^T (lane-local softmax) + defer-max; K/V dbuf prefetch,
// 1 barrier/tile; XCD-swizzled longest-strip-first grid.
// ---------------------------------------------------------------------------
#define SCALE2 0.18033688011112042f   // (1/sqrt(DK)) * log2(e)
#define THR    6.0f

__global__ __launch_bounds__(256, 4)
void attn_mfma(const __bf16* __restrict__ Qh, const __bf16* __restrict__ Kh,
               const __bf16* __restrict__ Vt, __bf16* __restrict__ Xb)
{
    __shared__ __bf16 Ks[2][64 * 64];
    __shared__ __bf16 Vs[2][64 * 64];
    __shared__ __bf16 Ps[64 * 64];

    const int t = threadIdx.x;
    const int wave = t >> 6, lane = t & 63;
    const int g4 = lane >> 4, l16 = lane & 15;
    const int fid   = blockIdx.x;
    const int xcd   = fid & 7;
    const int idx   = fid >> 3;
    const int strip = 31 - (idx >> 3);
    const int hb_id = xcd * 8 + (idx & 7);
    const int h = hb_id & 15, b = hb_id >> 4;
    const int qb = strip * 64;
    const size_t hb = (size_t)(b * H_ + h) * L_ * DK_;
    const __bf16* Qp = Qh + hb;
    const __bf16* Kp = Kh + hb;
    const __bf16* Vp = Vt + hb;
    const int qrow0 = qb + wave * 16;

    bf16x8 qf[2];
#pragma unroll
    for (int kk = 0; kk < 2; ++kk)
        qf[kk] = *reinterpret_cast<const bf16x8*>(
            &Qp[(size_t)(qrow0 + l16) * DK_ + kk * 32 + g4 * 8]);

    f32x4 O[4];
#pragma unroll
    for (int n = 0; n < 4; ++n) O[n] = {0.f, 0.f, 0.f, 0.f};
    float m_run = -1e30f, l_run = 0.f;

    const int ntile = strip + 1;
    stage_swz<2>(Kp, DK_, Ks[0], t);
    stage_swz<2>(Vp, L_, Vs[0], t);
    __syncthreads();

    int cur = 0;
    for (int it = 0; it < ntile; ++it) {
        if (it + 1 < ntile) {
            stage_swz<2>(Kp + (size_t)(it + 1) * 64 * DK_, DK_, Ks[cur ^ 1], t);
            stage_swz<2>(Vp + (it + 1) * 64, L_, Vs[cur ^ 1], t);
        }
        const int kv0 = it * 64;

        f32x4 st[4];
#pragma unroll
        for (int n = 0; n < 4; ++n) st[n] = {0.f, 0.f, 0.f, 0.f};
        __builtin_amdgcn_s_setprio(1);
#pragma unroll
        for (int kk = 0; kk < 2; ++kk) {
            bf16x8 kf[4];
#pragma unroll
            for (int n = 0; n < 4; ++n)
                kf[n] = lds_frag(Ks[cur], n * 16 + l16, kk * 64 + g4 * 16);
#pragma unroll
            for (int n = 0; n < 4; ++n)
                st[n] = MFMA16(kf[n], qf[kk], st[n]);
        }
        __builtin_amdgcn_s_setprio(0);

        if (it == strip) {
            const int qg = qrow0 + l16;
#pragma unroll
            for (int n = 0; n < 4; ++n)
#pragma unroll
                for (int r = 0; r < 4; ++r)
                    if (kv0 + n * 16 + g4 * 4 + r > qg) st[n][r] = -1e30f;
        }

        float mx = st[0][0];
#pragma unroll
        for (int n = 0; n < 4; ++n)
#pragma unroll
            for (int r = 0; r < 4; ++r)
                if (n + r) mx = fmaxf(mx, st[n][r]);
        mx = fmaxf(mx, __shfl_xor(mx, 16));
        mx = fmaxf(mx, __shfl_xor(mx, 32));
        const float mxs = mx * SCALE2;

        const bool grow = !__all(mxs - m_run <= THR);
        float al = 1.f;
        if (grow) {
            const float mn = fmaxf(m_run, mxs);
            al = exp2f(m_run - mn);
            m_run = mn;
        }

        char* Pw = (char*)Ps + (wave * 16 + l16) * 128;
        float lb = 0.f;
#pragma unroll
        for (int n = 0; n < 4; ++n) {
            bf16x4 pv;
#pragma unroll
            for (int r = 0; r < 4; ++r) {
                const float p = exp2f(fmaf(st[n][r], SCALE2, -m_run));
                lb += p;
                pv[r] = (__bf16)p;
            }
            *(bf16x4*)(Pw + ((n * 32 + g4 * 8) ^ ((l16 & 7) << 4))) = pv;
        }
        lb += __shfl_xor(lb, 16);
        lb += __shfl_xor(lb, 32);
        l_run = al * l_run + lb;

        if (grow) {
#pragma unroll
            for (int r = 0; r < 4; ++r) {
                const float alr = __shfl(al, g4 * 4 + r);
#pragma unroll
                for (int n = 0; n < 4; ++n) O[n][r] *= alr;
            }
        }

        const __bf16* Pr = Ps + wave * 16 * 64;
        __builtin_amdgcn_s_setprio(1);
#pragma unroll
        for (int kk = 0; kk < 2; ++kk) {
            bf16x8 pa = lds_frag(Pr, l16, kk * 64 + g4 * 16);
            bf16x8 vf[4];
#pragma unroll
            for (int n = 0; n < 4; ++n)
                vf[n] = lds_frag(Vs[cur], n * 16 + l16, kk * 64 + g4 * 16);
#pragma unroll
            for (int n = 0; n < 4; ++n)
                O[n] = MFMA16(pa, vf[n], O[n]);
        }
        __builtin_amdgcn_s_setprio(0);

        __syncthreads();
        cur ^= 1;
    }

    const float rl = 1.0f / l_run;
#pragma unroll
    for (int r = 0; r < 4; ++r) {
        const float inv = __shfl(rl, g4 * 4 + r);
        const int qrow = qrow0 + g4 * 4 + r;
#pragma unroll
        for (int n = 0; n < 4; ++n)
            Xb[((size_t)b * L_ + qrow) * D_ + h * DK_ + n * 16 + l16] =
                (__bf16)(O[n][r] * inv);
    }
}

// ---------------------------------------------------------------------------
extern "C" void kernel_launch(void* const* d_in, const int* in_sizes, int n_in,
                              void* d_out, int out_size, void* d_ws, size_t ws_size,
                              hipStream_t stream)
{
    (void)in_sizes; (void)n_in; (void)out_size; (void)ws_size;
    const float* query = (const float*)d_in[0];
    const float* key   = (const float*)d_in[1];
    const float* value = (const float*)d_in[2];
    const float* Wq = (const float*)d_in[4];
    const float* bq = (const float*)d_in[5];
    const float* Wk = (const float*)d_in[6];
    const float* bk = (const float*)d_in[7];
    const float* Wv = (const float*)d_in[8];
    const float* bv = (const float*)d_in[9];
    const float* Wo = (const float*)d_in[10];
    const float* bo = (const float*)d_in[11];

    const size_t SZ = (size_t)B_ * L_ * D_;
    const size_t WSZ = (size_t)D_ * D_;
    __bf16* wsb = (__bf16*)d_ws;
    __bf16* qb_ = wsb;                            // q|k|v bf16 contiguous (ASEG)
    __bf16* Qh  = wsb + 3 * SZ;
    __bf16* Kh  = wsb + 4 * SZ;
    __bf16* Vt  = wsb + 5 * SZ;
    __bf16* Xb  = wsb + 6 * SZ;
    __bf16* Wqkv = wsb + 7 * SZ;                  // Wq|Wk|Wv [3072][1024]
    __bf16* Wob  = Wqkv + 3 * WSZ;

    CastArgs ca;
    ca.s[0] = query; ca.s[1] = key; ca.s[2] = value;
    ca.s[3] = Wq; ca.s[4] = Wk; ca.s[5] = Wv; ca.s[6] = Wo;
    ca.d[0] = qb_; ca.d[1] = qb_ + SZ; ca.d[2] = qb_ + 2 * SZ;
    ca.d[3] = Wqkv; ca.d[4] = Wqkv + WSZ; ca.d[5] = Wqkv + 2 * WSZ; ca.d[6] = Wob;
    ca.n[0] = ca.n[1] = ca.n[2] = (int)SZ;
    ca.n[3] = ca.n[4] = ca.n[5] = ca.n[6] = (int)WSZ;
    cast_all<<<dim3(1024, 7), 256, 0, stream>>>(ca);

    QKVDst qd;
    qd.bq = bq; qd.bk = bk; qd.bvv = bv;
    qd.qh = Qh; qd.kh = Kh; qd.vt = Vt;

    // QKV: N=3072 -> 8 XCD x 4 m-panels x 24 n = 768 blocks (3/CU exact)
    gemm_big<3><<<768, 512, 0, stream>>>(qb_, Wqkv, nullptr, nullptr, 3 * D_, qd);
    attn_mfma<<<32 * H_ * B_, 256, 0, stream>>>(Qh, Kh, Vt, Xb);
    // out-proj: N=1024 -> 8 x 4 x 8 = 256 blocks (1/CU exact)
    gemm_big<2><<<256, 512, 0, stream>>>(Xb, Wob, bo, d_out, D_, qd);
}